// Round 1
// baseline (338.805 us; speedup 1.0000x reference)
//
#include <hip/hip_runtime.h>
#include <hip/hip_bf16.h>

#define T_DIM 800
#define B_DIM 32
#define V_DIM 1024
#define S_DIM 100
#define NEG2 (-1.4426950408889634e10f)   /* -1e10 * log2(e) */
#define L2E  (1.4426950408889634f)
#define LN2  (0.6931471805599453f)

#define NRED 1504
#define GRID_TOT (B_DIM + NRED)
#define BLK 256

// ws layout (32-bit slots):
// [0]                  : uint counter (zeroed by hipMemsetAsync each call)
// [1 .. 1+NRED)        : float partial sums (smoothing reduction)
// [1+NRED .. 1+NRED+32): float per-batch nll

__device__ __forceinline__ float lse2(float x, float y) {
    float m = fmaxf(x, y);
    float d = fminf(x, y) - m;               // <= 0
    return m + __builtin_amdgcn_logf(1.0f + __builtin_amdgcn_exp2f(d));
}
__device__ __forceinline__ float lse3(float x, float y, float z) {
    float m = fmaxf(fmaxf(x, y), z);
    float s = __builtin_amdgcn_exp2f(x - m) + __builtin_amdgcn_exp2f(y - m)
            + __builtin_amdgcn_exp2f(z - m);
    return m + __builtin_amdgcn_logf(s);
}

__device__ __forceinline__ void combine(int l, const float* partials, const float* nlls,
                                        const int* tlen, float* out)
{
    // deterministic: fixed lane-strided order + fixed shuffle tree
    float ps = 0.0f;
    for (int i = l; i < NRED; i += 64) ps += partials[i];
    for (int off = 32; off; off >>= 1) ps += __shfl_down(ps, off, 64);
    float cs = 0.0f;
    if (l < B_DIM) cs = nlls[l] / (float)tlen[l];
    for (int off = 32; off; off >>= 1) cs += __shfl_down(cs, off, 64);
    if (l == 0) {
        float smooth = -ps / (float)((long long)T_DIM * B_DIM * V_DIM);
        float ctc = cs / (float)B_DIM;
        out[0] = 0.9f * ctc + 0.1f * smooth;
    }
}

extern "C" __global__ void __launch_bounds__(BLK)
ctc_main(const float* __restrict__ lp,
         const int* __restrict__ tgt,
         const int* __restrict__ ilen,
         const int* __restrict__ tlen,
         float* __restrict__ ws,
         float* __restrict__ out)
{
    unsigned int* cnt = (unsigned int*)ws;
    float* partials = ws + 1;
    float* nlls = ws + 1 + NRED;
    const int bid = blockIdx.x;
    const int tid = threadIdx.x;

    if (bid < B_DIM) {
        // ---------------- CTC forward recursion: one wave per batch ----------------
        if (tid >= 64) return;
        const int l = tid;
        const int b = bid;
        const int len = ilen[b];
        const int tl  = tlen[b];
        // lane l owns extended states s = 4l .. 4l+3
        // odd states 4l+1, 4l+3 carry labels tgt[2l], tgt[2l+1]
        const int k0 = 2 * l, k1 = 2 * l + 1;
        int v1 = 0, v3 = 0; bool cs1 = false, cs3 = false;
        if (k0 < S_DIM) {
            v1 = tgt[b * S_DIM + k0];
            int vp = (k0 >= 1) ? tgt[b * S_DIM + k0 - 1] : -1;
            cs1 = (v1 != vp);
        }
        if (k1 < S_DIM) {
            v3 = tgt[b * S_DIM + k1];
            cs3 = (v3 != v1);
        }
        const size_t BV = (size_t)B_DIM * V_DIM;
        const float* lpb = lp + (size_t)b * V_DIM;

        // t = 0 init
        float eb = lpb[0], e1 = lpb[v1];
        float a0 = (l == 0) ? eb * L2E : NEG2;   // state 0 (blank)
        float a1 = (l == 0) ? e1 * L2E : NEG2;   // state 1 (first label)
        float a2 = NEG2, a3 = NEG2;

        // 2-deep emission prefetch pipeline
        float ebA = 0, e1A = 0, e3A = 0, ebB = 0, e1B = 0, e3B = 0;
        { const float* p = lpb + BV;     ebA = p[0]; e1A = p[v1]; e3A = p[v3]; }
        { const float* p = lpb + 2 * BV; ebB = p[0]; e1B = p[v1]; e3B = p[v3]; }

        for (int t = 1; t < len; ++t) {
            float h3 = __shfl_up(a3, 1, 64);   // left neighbor state 4l-1 (prev step)
            if (l == 0) h3 = NEG2;
            float ebb = ebA * L2E, e1b = e1A * L2E, e3b = e3A * L2E;
            ebA = ebB; e1A = e1B; e3A = e3B;
            int tp = t + 2;
            if (tp < len) {
                const float* p = lpb + (size_t)tp * BV;
                ebB = p[0]; e1B = p[v1]; e3B = p[v3];
            }
            float z1 = cs1 ? h3 : NEG2;   // skip source for state 4l+1 (s-2 = 4l-1)
            float z3 = cs3 ? a1 : NEG2;   // skip source for state 4l+3 (s-2 = 4l+1)
            float n0 = lse2(a0, h3) + ebb;           // blank
            float n1 = lse3(a1, a0, z1) + e1b;       // label tgt[2l]
            float n2 = lse2(a2, a1) + ebb;           // blank
            float n3 = lse3(a3, a2, z3) + e3b;       // label tgt[2l+1]
            a0 = n0; a1 = n1; a2 = n2; a3 = n3;
        }

        // extract alpha[2*tl] and alpha[2*tl - 1]
        int idx = 2 * tl;
        int lanehi = idx >> 2, rhi = idx & 3;
        int lanelo = (idx - 1) >> 2, rlo = (idx - 1) & 3;
        float h0 = __shfl(a0, lanehi, 64), h1s = __shfl(a1, lanehi, 64);
        float h2s = __shfl(a2, lanehi, 64), h3s = __shfl(a3, lanehi, 64);
        float vhi = (rhi == 0) ? h0 : (rhi == 1) ? h1s : (rhi == 2) ? h2s : h3s;
        float g0 = __shfl(a0, lanelo, 64), g1 = __shfl(a1, lanelo, 64);
        float g2 = __shfl(a2, lanelo, 64), g3 = __shfl(a3, lanelo, 64);
        float vlo = (rlo == 0) ? g0 : (rlo == 1) ? g1 : (rlo == 2) ? g2 : g3;
        float ll2 = lse2(vhi, vlo);
        float nll = -ll2 * LN2;
        if (nll > 1e9f) nll = 0.0f;   // zero_infinity

        int last = 0;
        if (l == 0) {
            nlls[b] = nll;
            __threadfence();
            unsigned old = __hip_atomic_fetch_add(cnt, 1u, __ATOMIC_ACQ_REL,
                                                  __HIP_MEMORY_SCOPE_AGENT);
            last = (old == GRID_TOT - 1) ? 1 : 0;
        }
        last = __shfl(last, 0, 64);
        if (last) combine(l, partials, nlls, tlen, out);
        return;
    }

    // ---------------- label-smoothing sum: grid-stride float4 reduction ----------------
    const int rb = bid - B_DIM;
    const float4* lp4 = (const float4*)lp;
    const int n4 = (T_DIM * B_DIM * V_DIM) / 4;
    const int NT = NRED * BLK;
    float s = 0.0f;
    for (int i = rb * BLK + tid; i < n4; i += NT) {
        float4 v = lp4[i];
        s += (v.x + v.y) + (v.z + v.w);
    }
    for (int off = 32; off; off >>= 1) s += __shfl_down(s, off, 64);
    __shared__ float red[BLK / 64];
    if ((tid & 63) == 0) red[tid >> 6] = s;
    __syncthreads();
    int last = 0;
    if (tid == 0) {
        float total = (red[0] + red[1]) + (red[2] + red[3]);
        partials[rb] = total;
        __threadfence();
        unsigned old = __hip_atomic_fetch_add(cnt, 1u, __ATOMIC_ACQ_REL,
                                              __HIP_MEMORY_SCOPE_AGENT);
        last = (old == GRID_TOT - 1) ? 1 : 0;
    }
    if (tid < 64) {
        last = __shfl(last, 0, 64);
        if (last) combine(tid, partials, nlls, tlen, out);
    }
}

extern "C" void kernel_launch(void* const* d_in, const int* in_sizes, int n_in,
                              void* d_out, int out_size, void* d_ws, size_t ws_size,
                              hipStream_t stream) {
    const float* lp  = (const float*)d_in[0];
    const int* tgt   = (const int*)d_in[1];
    const int* ilen  = (const int*)d_in[2];
    const int* tlen  = (const int*)d_in[3];
    float* out = (float*)d_out;
    float* ws  = (float*)d_ws;
    // zero only the done-counter (4 bytes) — partials/nlls are plain stores
    hipMemsetAsync(d_ws, 0, 4, stream);
    ctc_main<<<GRID_TOT, BLK, 0, stream>>>(lp, tgt, ilen, tlen, ws, out);
}

// Round 2
// 260.537 us; speedup vs baseline: 1.3004x; 1.3004x over previous
//
#include <hip/hip_runtime.h>
#include <hip/hip_bf16.h>

#define T_DIM 800
#define B_DIM 32
#define V_DIM 1024
#define S_DIM 100
#define NEG2 (-1.4426950408889634e10f)   /* -1e10 * log2(e) */
#define L2E  (1.4426950408889634f)
#define LN2  (0.6931471805599453f)

#define NRED 1504
#define GRID_TOT (B_DIM + NRED)
#define BLK 256
#define PFD 8   /* prefetch depth (iterations of slack) */

// ws layout (32-bit slots):
// [0]                  : uint counter (zeroed by hipMemsetAsync each call)
// [1 .. 1+NRED)        : float partial sums (smoothing reduction)
// [1+NRED .. 1+NRED+32): float per-batch nll

__device__ __forceinline__ float lse2(float x, float y) {
    float m = fmaxf(x, y);
    float d = fminf(x, y) - m;               // <= 0
    return m + __builtin_amdgcn_logf(1.0f + __builtin_amdgcn_exp2f(d));
}
__device__ __forceinline__ float lse3(float x, float y, float z) {
    float m = fmaxf(fmaxf(x, y), z);
    float s = __builtin_amdgcn_exp2f(x - m) + __builtin_amdgcn_exp2f(y - m)
            + __builtin_amdgcn_exp2f(z - m);
    return m + __builtin_amdgcn_logf(s);
}

__device__ __forceinline__ void combine(int l, const float* partials, const float* nlls,
                                        const int* tlen, float* out)
{
    // deterministic: fixed lane-strided order + fixed shuffle tree
    float ps = 0.0f;
    for (int i = l; i < NRED; i += 64) ps += partials[i];
    for (int off = 32; off; off >>= 1) ps += __shfl_down(ps, off, 64);
    float cs = 0.0f;
    if (l < B_DIM) cs = nlls[l] / (float)tlen[l];
    for (int off = 32; off; off >>= 1) cs += __shfl_down(cs, off, 64);
    if (l == 0) {
        float smooth = -ps / (float)((long long)T_DIM * B_DIM * V_DIM);
        float ctc = cs / (float)B_DIM;
        out[0] = 0.9f * ctc + 0.1f * smooth;
    }
}

extern "C" __global__ void __launch_bounds__(BLK)
ctc_main(const float* __restrict__ lp,
         const int* __restrict__ tgt,
         const int* __restrict__ ilen,
         const int* __restrict__ tlen,
         float* __restrict__ ws,
         float* __restrict__ out)
{
    unsigned int* cnt = (unsigned int*)ws;
    float* partials = ws + 1;
    float* nlls = ws + 1 + NRED;
    const int bid = blockIdx.x;
    const int tid = threadIdx.x;

    if (bid < B_DIM) {
        // ---------------- CTC forward recursion: one wave per batch ----------------
        if (tid >= 64) return;
        const int l = tid;
        const int b = bid;
        const int len = ilen[b];
        const int tl  = tlen[b];
        // lane l owns extended states s = 4l .. 4l+3
        // odd states 4l+1, 4l+3 carry labels tgt[2l], tgt[2l+1]
        const int k0 = 2 * l, k1 = 2 * l + 1;
        int v1 = 0, v3 = 0; bool cs1 = false, cs3 = false;
        if (k0 < S_DIM) {
            v1 = tgt[b * S_DIM + k0];
            int vp = (k0 >= 1) ? tgt[b * S_DIM + k0 - 1] : -1;
            cs1 = (v1 != vp);
        }
        if (k1 < S_DIM) {
            v3 = tgt[b * S_DIM + k1];
            cs3 = (v3 != v1);
        }
        const size_t BV = (size_t)B_DIM * V_DIM;
        const float* lpb = lp + (size_t)b * V_DIM;

        // t = 0 init
        float eb = lpb[0], e1 = lpb[v1];
        float a0 = (l == 0) ? eb * L2E : NEG2;   // state 0 (blank)
        float a1 = (l == 0) ? e1 * L2E : NEG2;   // state 1 (first label)
        float a2 = NEG2, a3 = NEG2;

        // PFD-deep emission prefetch queue (static indices only -> stays in VGPRs)
        float ebq[PFD], e1q[PFD], e3q[PFD];
        #pragma unroll
        for (int d = 0; d < PFD; ++d) {
            const float* p = lpb + (size_t)(1 + d) * BV;
            ebq[d] = p[0]; e1q[d] = p[v1]; e3q[d] = p[v3];
        }

        // fixed 800-step loop (t = 1..800), freeze-select for t >= len.
        // t = 800 is always frozen (len <= 800); its prefetch address is clamped.
        #pragma unroll 1
        for (int t0 = 1; t0 < 801; t0 += PFD) {
            #pragma unroll
            for (int d = 0; d < PFD; ++d) {
                const int t = t0 + d;
                float ebb = ebq[d] * L2E, e1b = e1q[d] * L2E, e3b = e3q[d] * L2E;
                // branch-free prefetch of step t+PFD into slot d (clamped addr)
                int tn = t + PFD; tn = (tn > T_DIM - 1) ? (T_DIM - 1) : tn;
                const float* p = lpb + (size_t)tn * BV;
                ebq[d] = p[0]; e1q[d] = p[v1]; e3q[d] = p[v3];

                float h3 = __shfl_up(a3, 1, 64);   // left neighbor state 4l-1
                if (l == 0) h3 = NEG2;
                float z1 = cs1 ? h3 : NEG2;   // skip source for state 4l+1
                float z3 = cs3 ? a1 : NEG2;   // skip source for state 4l+3
                float n0 = lse2(a0, h3) + ebb;           // blank
                float n1 = lse3(a1, a0, z1) + e1b;       // label tgt[2l]
                float n2 = lse2(a2, a1) + ebb;           // blank
                float n3 = lse3(a3, a2, z3) + e3b;       // label tgt[2l+1]
                bool live = (t < len);
                a0 = live ? n0 : a0;
                a1 = live ? n1 : a1;
                a2 = live ? n2 : a2;
                a3 = live ? n3 : a3;
            }
        }

        // extract alpha[2*tl] and alpha[2*tl - 1]
        int idx = 2 * tl;
        int lanehi = idx >> 2, rhi = idx & 3;
        int lanelo = (idx - 1) >> 2, rlo = (idx - 1) & 3;
        float h0 = __shfl(a0, lanehi, 64), h1s = __shfl(a1, lanehi, 64);
        float h2s = __shfl(a2, lanehi, 64), h3s = __shfl(a3, lanehi, 64);
        float vhi = (rhi == 0) ? h0 : (rhi == 1) ? h1s : (rhi == 2) ? h2s : h3s;
        float g0 = __shfl(a0, lanelo, 64), g1 = __shfl(a1, lanelo, 64);
        float g2 = __shfl(a2, lanelo, 64), g3 = __shfl(a3, lanelo, 64);
        float vlo = (rlo == 0) ? g0 : (rlo == 1) ? g1 : (rlo == 2) ? g2 : g3;
        float ll2 = lse2(vhi, vlo);
        float nll = -ll2 * LN2;
        if (nll > 1e9f) nll = 0.0f;   // zero_infinity

        int last = 0;
        if (l == 0) {
            nlls[b] = nll;
            __threadfence();
            unsigned old = __hip_atomic_fetch_add(cnt, 1u, __ATOMIC_ACQ_REL,
                                                  __HIP_MEMORY_SCOPE_AGENT);
            last = (old == GRID_TOT - 1) ? 1 : 0;
        }
        last = __shfl(last, 0, 64);
        if (last) combine(l, partials, nlls, tlen, out);
        return;
    }

    // ---------------- label-smoothing sum: grid-stride float4 reduction ----------------
    const int rb = bid - B_DIM;
    const float4* lp4 = (const float4*)lp;
    const int n4 = (T_DIM * B_DIM * V_DIM) / 4;
    const int NT = NRED * BLK;
    float s = 0.0f;
    for (int i = rb * BLK + tid; i < n4; i += NT) {
        float4 v = lp4[i];
        s += (v.x + v.y) + (v.z + v.w);
    }
    for (int off = 32; off; off >>= 1) s += __shfl_down(s, off, 64);
    __shared__ float red[BLK / 64];
    if ((tid & 63) == 0) red[tid >> 6] = s;
    __syncthreads();
    int last = 0;
    if (tid == 0) {
        float total = (red[0] + red[1]) + (red[2] + red[3]);
        partials[rb] = total;
        __threadfence();
        unsigned old = __hip_atomic_fetch_add(cnt, 1u, __ATOMIC_ACQ_REL,
                                              __HIP_MEMORY_SCOPE_AGENT);
        last = (old == GRID_TOT - 1) ? 1 : 0;
    }
    if (tid < 64) {
        last = __shfl(last, 0, 64);
        if (last) combine(tid, partials, nlls, tlen, out);
    }
}

extern "C" void kernel_launch(void* const* d_in, const int* in_sizes, int n_in,
                              void* d_out, int out_size, void* d_ws, size_t ws_size,
                              hipStream_t stream) {
    const float* lp  = (const float*)d_in[0];
    const int* tgt   = (const int*)d_in[1];
    const int* ilen  = (const int*)d_in[2];
    const int* tlen  = (const int*)d_in[3];
    float* out = (float*)d_out;
    float* ws  = (float*)d_ws;
    // zero only the done-counter (4 bytes) — partials/nlls are plain stores
    hipMemsetAsync(d_ws, 0, 4, stream);
    ctc_main<<<GRID_TOT, BLK, 0, stream>>>(lp, tgt, ilen, tlen, ws, out);
}

// Round 3
// 157.870 us; speedup vs baseline: 2.1461x; 1.6503x over previous
//
#include <hip/hip_runtime.h>
#include <hip/hip_bf16.h>

#define T_DIM 800
#define B_DIM 32
#define V_DIM 1024
#define S_DIM 100
#define L2E  (1.4426950408889634f)
#define LN2  (0.6931471805599453f)

#define CHUNK 40
#define ROWW  104
#define ENTRIES (CHUNK*ROWW)     /* 4160 */
#define LTHREADS 192
#define LPER 22                  /* ceil(4160/192) */

#define NRED 1504
#define GRID_TOT (B_DIM + NRED)
#define BLK 256

// ws layout (32-bit slots):
// [0]                  : uint counter (zeroed by hipMemsetAsync each call)
// [1 .. 1+NRED)        : float partial sums (smoothing reduction)
// [1+NRED .. 1+NRED+32): float per-batch nll

__device__ __forceinline__ void combine(int l, const float* partials, const float* nlls,
                                        const int* tlen, float* out)
{
    float ps = 0.0f;
    for (int i = l; i < NRED; i += 64) ps += partials[i];
    for (int off = 32; off; off >>= 1) ps += __shfl_down(ps, off, 64);
    float cs = 0.0f;
    if (l < B_DIM) cs = nlls[l] / (float)tlen[l];
    for (int off = 32; off; off >>= 1) cs += __shfl_down(cs, off, 64);
    if (l == 0) {
        float smooth = -ps / (float)((long long)T_DIM * B_DIM * V_DIM);
        float ctc = cs / (float)B_DIM;
        out[0] = 0.9f * ctc + 0.1f * smooth;
    }
}

extern "C" __global__ void __launch_bounds__(BLK)
ctc_main(const float* __restrict__ lp,
         const int* __restrict__ tgt,
         const int* __restrict__ ilen,
         const int* __restrict__ tlen,
         float* __restrict__ ws,
         float* __restrict__ out)
{
    __shared__ float buf[2][ENTRIES];
    __shared__ int   tgtS[S_DIM];
    __shared__ float red[BLK / 64];

    unsigned int* cnt = (unsigned int*)ws;
    float* partials = ws + 1;
    float* nlls = ws + 1 + NRED;
    const int bid = blockIdx.x;
    const int tid = threadIdx.x;

    if (bid < B_DIM) {
        const int b = bid;
        const int len = ilen[b];      // uniform in block
        const int tl  = tlen[b];
        const int wav = tid >> 6;
        const int l   = tid & 63;
        const int NC  = (len - 1 + CHUNK - 1) / CHUNK;   // steps t=1..len-1

        // stage targets into LDS (loader threads 64..163)
        if (tid >= 64 && tid < 64 + S_DIM) tgtS[tid - 64] = tgt[b * S_DIM + (tid - 64)];
        __syncthreads();   // A: tgtS ready

        // ---------------- per-role state ----------------
        // consumer (wave 0) state
        float p0 = 0, p1 = 0, p2 = 0, p3 = 0;
        int   el = 0;
        float h3p = 0; int enb = 0;
        float cs1f = 0, cs3f = 0;
        int kk1 = 101, kk3 = 101;
        // loader state
        int   woffs[LPER]; int doffs[LPER]; float zmul[LPER];

        if (wav == 0) {
            __builtin_amdgcn_s_setprio(1);
            int v1 = 0, v3 = 0;
            if (l <= 49) {
                v1 = tgtS[2 * l];
                int vp = (l >= 1) ? tgtS[2 * l - 1] : -1;
                cs1f = (v1 != vp) ? 1.0f : 0.0f;
                v3 = tgtS[2 * l + 1];
                cs3f = (v3 != v1) ? 1.0f : 0.0f;
                kk1 = 1 + 2 * l; kk3 = 2 + 2 * l;
            }
            // t = 0 init (direct global; latency overlapped with chunk0 staging)
            float eb0 = lp[b * V_DIM];
            float e10 = lp[b * V_DIM + v1];
            p0 = (l == 0) ? __builtin_amdgcn_exp2f(eb0 * L2E) : 0.0f;
            p1 = (l == 0) ? __builtin_amdgcn_exp2f(e10 * L2E) : 0.0f;
            h3p = __shfl_up(p3, 1, 64);
            enb = __shfl_up(el, 1, 64);
        } else {
            const int j = tid - 64;   // 0..191
            #pragma unroll
            for (int u = 0; u < LPER; ++u) {
                int i = j + u * LTHREADS; if (i > ENTRIES - 1) i = ENTRIES - 1;
                int tt = (int)(((long long)i * 40330) >> 22);  // i / 104
                int k  = i - tt * ROWW;
                int v  = (k >= 1 && k <= 100) ? tgtS[k - 1] : 0;
                woffs[u] = tt * (B_DIM * V_DIM) + v;
                doffs[u] = tt * ROWW + k;
                zmul[u]  = (k <= 100) ? 1.0f : 0.0f;
            }
            // stage chunk 0 (t = 1..CHUNK)
            {
                const float* src = lp + (size_t)1 * (B_DIM * V_DIM) + b * V_DIM;
                float* dst = buf[0];
                #pragma unroll
                for (int u = 0; u < LPER; ++u) {
                    float val = src[woffs[u]];
                    dst[doffs[u]] = zmul[u] * __builtin_amdgcn_exp2f(val * L2E);
                }
            }
        }
        __syncthreads();   // B: buf0 ready

        float nll = 0.0f;

        for (int c = 0; c < NC; ++c) {
            if (wav == 0) {
                // ---------------- consume chunk c ----------------
                const int tbase = 1 + c * CHUNK;
                int nsteps = len - tbase; if (nsteps > CHUNK) nsteps = CHUNK;
                const float* rowp = buf[c & 1];
                int ri = 0;
                float ebc = rowp[0], e1c = rowp[kk1], e3c = rowp[kk3];

#define STEP do { \
    const float* rn_ = rowp + ((ri + 1 < CHUNK) ? ROWW : 0); \
    float ebn_ = rn_[0], e1n_ = rn_[kk1], e3n_ = rn_[kk3]; \
    float mz_ = fmaxf(fmaxf(p0, p1), fmaxf(p2, p3)); \
    int elA_ = (mz_ == 0.0f) ? enb : el; \
    int dlt_ = enb - elA_; dlt_ = (dlt_ < -120) ? -120 : ((dlt_ > 120) ? 120 : dlt_); \
    float sf_ = __int_as_float((dlt_ + 127) << 23); \
    float h3s_ = (l == 0) ? 0.0f : h3p * sf_; \
    float n0_ = (p0 + h3s_) * ebc; \
    float n1_ = fmaf(cs1f, h3s_, p0 + p1) * e1c; \
    float n2_ = (p1 + p2) * ebc; \
    float n3_ = fmaf(cs3f, p1, p2 + p3) * e3c; \
    p0 = n0_; p1 = n1_; p2 = n2_; p3 = n3_; el = elA_; \
    h3p = __shfl_up(p3, 1, 64); enb = __shfl_up(el, 1, 64); \
    ebc = ebn_; e1c = e1n_; e3c = e3n_; rowp += ROWW; ++ri; \
} while (0)

#define RENORM do { \
    float m_ = fmaxf(fmaxf(p0, p1), fmaxf(p2, p3)); \
    unsigned er_ = (__float_as_uint(m_) >> 23) & 255u; \
    float sc_ = __uint_as_float((254u - er_) << 23); \
    p0 *= sc_; p1 *= sc_; p2 *= sc_; p3 *= sc_; el += (int)er_ - 127; \
} while (0)

                int fg = nsteps >> 2, rem = nsteps & 3;
                for (int g = 0; g < fg; ++g) { STEP; STEP; STEP; STEP; RENORM; }
                for (int r = 0; r < rem; ++r) { STEP; }
                if (rem) RENORM;
            } else if (c + 1 < NC) {
                // ---------------- stage chunk c+1 ----------------
                const int cc = c + 1;
                const int tb = 1 + cc * CHUNK;
                float* dst = buf[cc & 1];
                if (tb + CHUNK <= T_DIM) {
                    const float* src = lp + (size_t)tb * (B_DIM * V_DIM) + b * V_DIM;
                    #pragma unroll
                    for (int u = 0; u < LPER; ++u) {
                        float val = src[woffs[u]];
                        dst[doffs[u]] = zmul[u] * __builtin_amdgcn_exp2f(val * L2E);
                    }
                } else {
                    const int j = tid - 64;
                    #pragma unroll
                    for (int u = 0; u < LPER; ++u) {
                        int i = j + u * LTHREADS; if (i > ENTRIES - 1) i = ENTRIES - 1;
                        int tt = (int)(((long long)i * 40330) >> 22);
                        int k  = i - tt * ROWW;
                        int t  = tb + tt; if (t > T_DIM - 1) t = T_DIM - 1;
                        int v  = (k >= 1 && k <= 100) ? tgtS[k - 1] : 0;
                        float val = lp[((size_t)t * B_DIM + b) * V_DIM + v];
                        dst[tt * ROWW + k] = ((k <= 100) ? 1.0f : 0.0f)
                                             * __builtin_amdgcn_exp2f(val * L2E);
                    }
                }
            }
            __syncthreads();
        }

        if (wav == 0) {
            // extract alpha[2*tl] and alpha[2*tl-1] in log2 domain
            int idx = 2 * tl;
            int lanehi = idx >> 2, rhi = idx & 3;
            int lanelo = (idx - 1) >> 2, rlo = (idx - 1) & 3;
            float q0 = __shfl(p0, lanehi, 64), q1 = __shfl(p1, lanehi, 64);
            float q2 = __shfl(p2, lanehi, 64), q3 = __shfl(p3, lanehi, 64);
            int   eh = __shfl(el, lanehi, 64);
            float ph = (rhi == 0) ? q0 : (rhi == 1) ? q1 : (rhi == 2) ? q2 : q3;
            float g0 = __shfl(p0, lanelo, 64), g1 = __shfl(p1, lanelo, 64);
            float g2 = __shfl(p2, lanelo, 64), g3 = __shfl(p3, lanelo, 64);
            int   eo = __shfl(el, lanelo, 64);
            float pl = (rlo == 0) ? g0 : (rlo == 1) ? g1 : (rlo == 2) ? g2 : g3;
            float vhi = (ph > 0.0f) ? __builtin_amdgcn_logf(ph) + (float)eh : -3.0e9f;
            float vlo = (pl > 0.0f) ? __builtin_amdgcn_logf(pl) + (float)eo : -3.0e9f;
            float m = fmaxf(vhi, vlo);
            float d = fminf(vhi, vlo) - m;
            float ll2 = m + __builtin_amdgcn_logf(1.0f + __builtin_amdgcn_exp2f(d));
            nll = -ll2 * LN2;
            if (!(nll < 1e9f)) nll = 0.0f;   // zero_infinity (also NaN-safe)

            int last = 0;
            if (l == 0) {
                nlls[b] = nll;
                __threadfence();
                unsigned old = __hip_atomic_fetch_add(cnt, 1u, __ATOMIC_ACQ_REL,
                                                      __HIP_MEMORY_SCOPE_AGENT);
                last = (old == GRID_TOT - 1) ? 1 : 0;
            }
            last = __shfl(last, 0, 64);
            if (last) combine(l, partials, nlls, tlen, out);
        }
        return;
    }

    // ---------------- label-smoothing sum: grid-stride float4 reduction ----------------
    const int rb = bid - B_DIM;
    const float4* lp4 = (const float4*)lp;
    const int n4 = (T_DIM * B_DIM * V_DIM) / 4;
    const int NT = NRED * BLK;
    float s = 0.0f;
    for (int i = rb * BLK + tid; i < n4; i += NT) {
        float4 v = lp4[i];
        s += (v.x + v.y) + (v.z + v.w);
    }
    for (int off = 32; off; off >>= 1) s += __shfl_down(s, off, 64);
    if ((tid & 63) == 0) red[tid >> 6] = s;
    __syncthreads();
    int last = 0;
    if (tid == 0) {
        float total = (red[0] + red[1]) + (red[2] + red[3]);
        partials[rb] = total;
        __threadfence();
        unsigned old = __hip_atomic_fetch_add(cnt, 1u, __ATOMIC_ACQ_REL,
                                              __HIP_MEMORY_SCOPE_AGENT);
        last = (old == GRID_TOT - 1) ? 1 : 0;
    }
    if (tid < 64) {
        last = __shfl(last, 0, 64);
        if (last) combine(tid, partials, nlls, tlen, out);
    }
}

extern "C" void kernel_launch(void* const* d_in, const int* in_sizes, int n_in,
                              void* d_out, int out_size, void* d_ws, size_t ws_size,
                              hipStream_t stream) {
    const float* lp  = (const float*)d_in[0];
    const int* tgt   = (const int*)d_in[1];
    const int* ilen  = (const int*)d_in[2];
    const int* tlen  = (const int*)d_in[3];
    float* out = (float*)d_out;
    float* ws  = (float*)d_ws;
    hipMemsetAsync(d_ws, 0, 4, stream);
    ctc_main<<<GRID_TOT, BLK, 0, stream>>>(lp, tgt, ilen, tlen, ws, out);
}